// Round 15
// baseline (206.776 us; speedup 1.0000x reference)
//
#include <hip/hip_runtime.h>
#include <hip/hip_bf16.h>
#include <hip/hip_fp8.h>

#define D_DIM 768
#define B_DIM 8192
#define NT 64           // tile grid dim (8192/128)
#define NTILES 2080     // NT*(NT+1)/2 upper-triangle tiles
#define BM 128

typedef __attribute__((ext_vector_type(4))) float f32x4;
typedef __attribute__((ext_vector_type(2))) float f32x2;
typedef __attribute__((ext_vector_type(4))) int i32x4;
typedef __attribute__((ext_vector_type(8))) int i32x8;

// ws layout (bytes)
#define WS_XB   0                               // fp8[8192*768]    = 6,291,456
#define WS_SQ   6291456                         // float[8192]      = 32,768
#define WS_CAND 6324224                         // float[8192*64*6] = 12,582,912
#define WS_ACC  18907136                        // float[1]
#define WS_TKT  18907140                        // uint[1]

__device__ __forceinline__ void gl_lds16(const void* g, void* lds) {
  __builtin_amdgcn_global_load_lds(
      (const __attribute__((address_space(1))) unsigned int*)g,
      (__attribute__((address_space(3))) unsigned int*)lds, 16, 0, 0);
}

// sort 4 values ascending (5-comparator network, 10 VALU)
__device__ __forceinline__ void sort4(float& a0, float& a1, float& a2,
                                      float& a3) {
  const float s1 = fminf(a0, a1), t1 = fmaxf(a0, a1);
  const float s2 = fminf(a2, a3), t2 = fmaxf(a2, a3);
  const float lo = fminf(s1, s2), m1 = fmaxf(s1, s2);
  const float hi = fmaxf(t1, t2), m2 = fminf(t1, t2);
  a0 = lo;
  a1 = fminf(m1, m2);
  a2 = fmaxf(m1, m2);
  a3 = hi;
}

// merge sorted a[0..3] into sorted v[0..5], keep 6 smallest (closed-form
// k-th-of-union; nested fminf chains fuse to v_min3_f32)
__device__ __forceinline__ void mrg46(float a0, float a1, float a2, float a3,
                                      float* v) {
  const float x00 = fmaxf(v[0], a0);
  const float x01 = fmaxf(v[0], a1), x10 = fmaxf(v[1], a0);
  const float x02 = fmaxf(v[0], a2), x11 = fmaxf(v[1], a1),
              x20 = fmaxf(v[2], a0);
  const float x03 = fmaxf(v[0], a3), x12 = fmaxf(v[1], a2),
              x21 = fmaxf(v[2], a1), x30 = fmaxf(v[3], a0);
  const float x13 = fmaxf(v[1], a3), x22 = fmaxf(v[2], a2),
              x31 = fmaxf(v[3], a1), x40 = fmaxf(v[4], a0);
  const float m0 = fminf(v[0], a0);
  const float m1 = fminf(fminf(v[1], a1), x00);
  const float m2 = fminf(fminf(fminf(v[2], a2), x01), x10);
  const float m3 = fminf(fminf(fminf(v[3], a3), x02), fminf(x11, x20));
  const float m4 = fminf(fminf(fminf(v[4], x03), x12), fminf(x21, x30));
  const float m5 = fminf(fminf(fminf(v[5], x13), x22), fminf(x31, x40));
  v[0] = m0; v[1] = m1; v[2] = m2; v[3] = m3; v[4] = m4; v[5] = m5;
}

// merge sorted b[0..5] into sorted v[0..5], keep 6 smallest
__device__ __forceinline__ void mrg66(const float* b, float* v) {
  const float x00 = fmaxf(v[0], b[0]);
  const float x01 = fmaxf(v[0], b[1]), x10 = fmaxf(v[1], b[0]);
  const float x02 = fmaxf(v[0], b[2]), x11 = fmaxf(v[1], b[1]),
              x20 = fmaxf(v[2], b[0]);
  const float x03 = fmaxf(v[0], b[3]), x12 = fmaxf(v[1], b[2]),
              x21 = fmaxf(v[2], b[1]), x30 = fmaxf(v[3], b[0]);
  const float x04 = fmaxf(v[0], b[4]), x13 = fmaxf(v[1], b[3]),
              x22 = fmaxf(v[2], b[2]), x31 = fmaxf(v[3], b[1]),
              x40 = fmaxf(v[4], b[0]);
  const float m0 = fminf(v[0], b[0]);
  const float m1 = fminf(fminf(v[1], b[1]), x00);
  const float m2 = fminf(fminf(fminf(v[2], b[2]), x01), x10);
  const float m3 = fminf(fminf(fminf(v[3], b[3]), x02), fminf(x11, x20));
  const float m4 =
      fminf(fminf(fminf(v[4], b[4]), x03), fminf(fminf(x12, x21), x30));
  const float m5 = fminf(fminf(fminf(v[5], b[5]), x04),
                         fminf(fminf(x13, x22), fminf(x31, x40)));
  v[0] = m0; v[1] = m1; v[2] = m2; v[3] = m3; v[4] = m4; v[5] = m5;
}

// band-blocked triangle order (16x16-tile blocks, rt-major inside). g in [0,2080).
__device__ __forceinline__ void tile_decode(int g, int& rt, int& ct) {
  int base = 0;
  for (int s = 0; s < 4; ++s) {
    for (int cb = s; cb < 4; ++cb) {
      const int sz = (cb == s) ? 136 : 256;
      if (g < base + sz) {
        int loc = g - base;
        if (cb == s) {
          int r = 0;
          while (loc >= 16 - r) {
            loc -= 16 - r;
            ++r;
          }
          rt = s * 16 + r;
          ct = cb * 16 + r + loc;
        } else {
          rt = s * 16 + (loc >> 4);
          ct = cb * 16 + (loc & 15);
        }
        return;
      }
      base += sz;
    }
  }
  rt = 0;
  ct = 0;
}

// kernel 1: cast fp32 -> fp8 e4m3 (OCP), row sum-of-squares of the DECODED fp8
// values (so self-distance rsq+rsq-2*G(i,i) stays ~0). Verified round 9/10.
__global__ __launch_bounds__(256) void cast_sq_kernel(
    const float* __restrict__ x, unsigned char* __restrict__ xb,
    float* __restrict__ sq, float* __restrict__ acc,
    unsigned int* __restrict__ tkt) {
  const int t = threadIdx.x;
  const int w = t >> 6, lane = t & 63;
  const int row = blockIdx.x * 4 + w;
  if (blockIdx.x == 0) {
    if (t == 0) acc[0] = 0.0f;
    if (t == 1) tkt[0] = 0u;
  }
  const f32x4* xr = (const f32x4*)(x + (size_t)row * D_DIM);
  unsigned int* xbr = (unsigned int*)(xb + (size_t)row * D_DIM);
  float s = 0.0f;
#pragma unroll
  for (int c = 0; c < 3; ++c) {
    const int idx = c * 64 + lane;
    f32x4 v = xr[idx];
    unsigned int p = 0;
#pragma unroll
    for (int e = 0; e < 4; ++e) {
      __hip_fp8_e4m3 h(v[e]);
      const float d = (float)h;
      s += d * d;
      p |= ((unsigned int)h.__x) << (8 * e);
    }
    xbr[idx] = p;
  }
#pragma unroll
  for (int off = 32; off > 0; off >>= 1) s += __shfl_down(s, off, 64);
  if (lane == 0) sq[row] = s;
}

// ------- kernel 2: MX-fp8 K=128, single-buffer staging, 4 blocks/CU -------
// Round-14 verified math. LDS 64->33 KB: single 32 KB section buffer; staging
// of section s+1 is issued BETWEEN the post-read barrier and the MFMA cluster,
// so gl_lds latency hides under the MFMA phase; next section's VMW(0)+BAR
// certifies it. Same 2 barriers/section. 4 blocks/CU (16 waves, 4/SIMD) gives
// the cross-block TLP the 2-block dbuf structure lacked (no pipe >40% there).
// distS now stores full d^2 (writer adds rsq) -> col-side loses 128 adds/thread.
#define VMW(N) asm volatile("s_waitcnt vmcnt(" #N ")" ::: "memory")
#define BAR()                         \
  {                                   \
    asm volatile("" ::: "memory");    \
    __builtin_amdgcn_s_barrier();     \
    asm volatile("" ::: "memory");    \
  }

__global__ __launch_bounds__(256, 4) void knn_gemm_kernel(
    const unsigned char* __restrict__ xb, const float* __restrict__ sq,
    float* __restrict__ cand) {
  __shared__ __align__(16) char smem[33792];
  const int t = threadIdx.x;
  const int lane = t & 63, w = t >> 6;
  const int wm = w >> 1, wn = w & 1;  // 2x2 wave grid; wave tile 64x64
  const int quad = lane >> 4, m16 = lane & 15;

  // XCD chunking (2080 = 8*260, bijective) + band-blocked decode
  const int g = (blockIdx.x & 7) * (NTILES / 8) + (blockIdx.x >> 3);
  int rt, ct;
  tile_decode(g, rt, ct);
  const bool offdiag = (ct > rt);
  const int rowBase = rt * BM, colBase = ct * BM;

  // staging: thread t covers rows (t>>3)+32q, slot t&7; inverse slot swizzle on
  // the global source. (row&3) and ((row>>2)&1) are invariant under row+=32.
  const int sR = t >> 3, sS = t & 7;
  const int q_src = ((sS >> 1) - sR) & 3;
  const int h_src = ((sS & 1) - (sR >> 2)) & 1;
  const int srcOff = q_src * 32 + h_src * 16;
  const unsigned char* pA = xb + (size_t)(rowBase + sR) * D_DIM + srcOff;
  const unsigned char* pB = xb + (size_t)(colBase + sR) * D_DIM + srcOff;

  // fragment read offsets (within a row's 128 B)
  const int pairOff = ((quad + m16) & 3) * 32;
  const int bitOff = ((m16 >> 2) & 1) * 16;
  const int laneLo = m16 * 128 + pairOff + bitOff;
  const int laneHi = m16 * 128 + pairOff + (bitOff ^ 16);
  const int aRow = wm * 8192;
  const int bRow = wn * 8192;

  float rsq[16];
#pragma unroll
  for (int i = 0; i < 4; ++i)
#pragma unroll
    for (int r = 0; r < 4; ++r)
      rsq[i * 4 + r] = sq[rowBase + wm * 64 + i * 16 + quad * 4 + r];
  float csq[4];
#pragma unroll
  for (int j = 0; j < 4; ++j) csq[j] = sq[colBase + wn * 64 + j * 16 + m16];

  f32x4 acv[4][4];
  const f32x4 zero = {0.0f, 0.0f, 0.0f, 0.0f};
#pragma unroll
  for (int i = 0; i < 4; ++i)
#pragma unroll
    for (int j = 0; j < 4; ++j) acv[i][j] = zero;

#define STAGE(P, KOFF, REGION)                                          \
  {                                                                     \
    _Pragma("unroll") for (int q = 0; q < 4; ++q)                       \
        gl_lds16((P) + (KOFF) + q * 32 * D_DIM,                         \
                 smem + (REGION) + q * 4096 + t * 16);                  \
  }

  i32x8 aF[4], bF[4];
#define LDA(BASE)                                                            \
  {                                                                          \
    _Pragma("unroll") for (int ii = 0; ii < 4; ++ii) {                       \
      i32x4 lo = *(const i32x4*)(smem + (BASE) + aRow + ii * 2048 + laneLo); \
      i32x4 hi = *(const i32x4*)(smem + (BASE) + aRow + ii * 2048 + laneHi); \
      __builtin_memcpy(&aF[ii], &lo, 16);                                    \
      __builtin_memcpy(((char*)&aF[ii]) + 16, &hi, 16);                      \
    }                                                                        \
  }
#define LDB(BASE)                                                            \
  {                                                                          \
    _Pragma("unroll") for (int j = 0; j < 4; ++j) {                          \
      i32x4 lo = *(const i32x4*)(smem + (BASE) + bRow + j * 2048 + laneLo);  \
      i32x4 hi = *(const i32x4*)(smem + (BASE) + bRow + j * 2048 + laneHi);  \
      __builtin_memcpy(&bF[j], &lo, 16);                                     \
      __builtin_memcpy(((char*)&bF[j]) + 16, &hi, 16);                       \
    }                                                                        \
  }
#define MFMAS16                                                              \
  {                                                                          \
    __builtin_amdgcn_s_setprio(1);                                           \
    _Pragma("unroll") for (int ii = 0; ii < 4; ++ii)                         \
        _Pragma("unroll") for (int j = 0; j < 4; ++j)                        \
            acv[ii][j] = __builtin_amdgcn_mfma_scale_f32_16x16x128_f8f6f4(   \
                aF[ii], bF[j], acv[ii][j], 0, 0, 0, 0x7F7F7F7F, 0,           \
                0x7F7F7F7F);                                                 \
    __builtin_amdgcn_s_setprio(0);                                           \
  }

  // prologue: stage section 0 into the single buffer (A at 0, B at 16384)
  STAGE(pA, 0, 0);
  STAGE(pB, 0, 16384);

#pragma unroll
  for (int s = 0; s < 6; ++s) {
    VMW(0);   // own staging loads arrived (each wave drains its own pre-barrier)
    BAR();    // -> all waves' staging visible
    LDA(0);
    LDB(16384);
    BAR();    // lgkm drained per-wave pre-barrier -> buffer free to overwrite
    if (s < 5) {
      STAGE(pA, (s + 1) * 128, 0);       // flies during the MFMA phase
      STAGE(pB, (s + 1) * 128, 16384);
    }
    MFMAS16;
  }

  // ---------------- epilogue: 2 groups of 64 rows, split row/col duty ----------------
  float* distS = (float*)smem;             // [64][132] f32 = 33792 B (full d^2)

#pragma unroll
  for (int q = 0; q < 6; ++q) {
  }
  float colA[6], colB[6];
#pragma unroll
  for (int q = 0; q < 6; ++q) colA[q] = colB[q] = 1e30f;

#pragma unroll
  for (int gg = 0; gg < 2; ++gg) {
    BAR();  // all ds_reads of the K-loop buffer retired before overwrite
    if (wm == gg) {
      // full d^2 = (csq[col] + rsq[row]) - 2G
#pragma unroll
      for (int ii = 0; ii < 4; ++ii)
#pragma unroll
        for (int j = 0; j < 4; ++j)
#pragma unroll
          for (int r = 0; r < 4; ++r)
            distS[(ii * 16 + quad * 4 + r) * 132 + wn * 64 + j * 16 + m16] =
                (csq[j] + rsq[ii * 4 + r]) - 2.0f * acv[ii][j][r];
    }
    BAR();
    if (t < 128) {
      // row-side: 2 thr/row x 64 cols; dual independent chains (even/odd batch)
      const int row_l = t >> 1, half = t & 1;
      const float* drow = distS + row_l * 132 + half * 64;
      float vA[6], vB[6];
      {
        f32x4 dv = *(const f32x4*)(drow);
        float w0 = dv[0], w1 = dv[1], w2 = dv[2], w3 = dv[3];
        sort4(w0, w1, w2, w3);
        vA[0] = w0; vA[1] = w1; vA[2] = w2; vA[3] = w3;
        vA[4] = 1e30f; vA[5] = 1e30f;
      }
      {
        f32x4 dv = *(const f32x4*)(drow + 4);
        float w0 = dv[0], w1 = dv[1], w2 = dv[2], w3 = dv[3];
        sort4(w0, w1, w2, w3);
        vB[0] = w0; vB[1] = w1; vB[2] = w2; vB[3] = w3;
        vB[4] = 1e30f; vB[5] = 1e30f;
      }
#pragma unroll
      for (int k = 2; k < 16; k += 2) {
        {
          f32x4 dv = *(const f32x4*)(drow + k * 4);
          float w0 = dv[0], w1 = dv[1], w2 = dv[2], w3 = dv[3];
          sort4(w0, w1, w2, w3);
          mrg46(w0, w1, w2, w3, vA);
        }
        {
          f32x4 dv = *(const f32x4*)(drow + k * 4 + 4);
          float w0 = dv[0], w1 = dv[1], w2 = dv[2], w3 = dv[3];
          sort4(w0, w1, w2, w3);
          mrg46(w0, w1, w2, w3, vB);
        }
      }
      mrg66(vB, vA);
      float b[6];
#pragma unroll
      for (int q = 0; q < 6; ++q) b[q] = __shfl_xor(vA[q], 1, 64);
      mrg66(b, vA);
      if (half == 0) {
        const int grow = rowBase + gg * 64 + row_l;
        float* o6 = cand + (size_t)(grow * NT + ct) * 6;
        f32x2 w0 = {fmaxf(vA[0], 0.0f), fmaxf(vA[1], 0.0f)};
        f32x2 w1 = {fmaxf(vA[2], 0.0f), fmaxf(vA[3], 0.0f)};
        f32x2 w2 = {fmaxf(vA[4], 0.0f), fmaxf(vA[5], 0.0f)};
        *(f32x2*)o6 = w0;
        *(f32x2*)(o6 + 2) = w1;
        *(f32x2*)(o6 + 4) = w2;
      }
    } else if (offdiag) {
      // col-side: 1 thr/col; distS already holds full d^2; dual chains
      const int col = t - 128;
#pragma unroll
      for (int r4 = 0; r4 < 16; r4 += 2) {
        {
          const int rr = r4 * 4;
          float w0 = distS[(rr + 0) * 132 + col];
          float w1 = distS[(rr + 1) * 132 + col];
          float w2 = distS[(rr + 2) * 132 + col];
          float w3 = distS[(rr + 3) * 132 + col];
          sort4(w0, w1, w2, w3);
          mrg46(w0, w1, w2, w3, colA);
        }
        {
          const int rr = (r4 + 1) * 4;
          float w0 = distS[(rr + 0) * 132 + col];
          float w1 = distS[(rr + 1) * 132 + col];
          float w2 = distS[(rr + 2) * 132 + col];
          float w3 = distS[(rr + 3) * 132 + col];
          sort4(w0, w1, w2, w3);
          mrg46(w0, w1, w2, w3, colB);
        }
      }
    }
  }
  if (offdiag && t >= 128) {
    mrg66(colB, colA);
    const int colg = colBase + (t - 128);
    float* o6 = cand + (size_t)(colg * NT + rt) * 6;
    f32x2 w0 = {fmaxf(colA[0], 0.0f), fmaxf(colA[1], 0.0f)};
    f32x2 w1 = {fmaxf(colA[2], 0.0f), fmaxf(colA[3], 0.0f)};
    f32x2 w2 = {fmaxf(colA[4], 0.0f), fmaxf(colA[5], 0.0f)};
    *(f32x2*)o6 = w0;
    *(f32x2*)(o6 + 2) = w1;
    *(f32x2*)(o6 + 4) = w2;
  }
}

// kernel 3: per-row merge of 64 chunk-candidates (each already sorted-6)
// via two independent mrg66 chains -> sqrt -> log -> global sum, fused
// finalize via ticket (last block writes the output).
__global__ __launch_bounds__(256) void knn_merge_kernel(
    const float* __restrict__ cand, float* __restrict__ acc,
    unsigned int* __restrict__ tkt, float* __restrict__ out) {
  const int t = threadIdx.x;
  const int r = blockIdx.x * 32 + (t >> 3);
  const float* cr = cand + (size_t)r * (NT * 6) + (size_t)(t & 7) * 48;
  float vA[6], vB[6];
  {
    f32x4 d0 = *(const f32x4*)(cr);
    f32x4 d1 = *(const f32x4*)(cr + 4);
    f32x4 d2 = *(const f32x4*)(cr + 8);
    vA[0] = d0[0]; vA[1] = d0[1]; vA[2] = d0[2]; vA[3] = d0[3];
    vA[4] = d1[0]; vA[5] = d1[1];
    vB[0] = d1[2]; vB[1] = d1[3]; vB[2] = d2[0]; vB[3] = d2[1];
    vB[4] = d2[2]; vB[5] = d2[3];
  }
#pragma unroll
  for (int c = 1; c < 4; ++c) {
    f32x4 d0 = *(const f32x4*)(cr + c * 12);
    f32x4 d1 = *(const f32x4*)(cr + c * 12 + 4);
    f32x4 d2 = *(const f32x4*)(cr + c * 12 + 8);
    float b0[6] = {d0[0], d0[1], d0[2], d0[3], d1[0], d1[1]};
    mrg66(b0, vA);
    float b1[6] = {d1[2], d1[3], d2[0], d2[1], d2[2], d2[3]};
    mrg66(b1, vB);
  }
  mrg66(vB, vA);
#pragma unroll
  for (int st = 1; st <= 4; st <<= 1) {
    float b[6];
#pragma unroll
    for (int q = 0; q < 6; ++q) b[q] = __shfl_xor(vA[q], st, 64);
    mrg66(b, vA);
  }
  float term = 0.0f;
  if ((t & 7) == 0) {
    // vA sorted ascending on d^2: vA[0]=self (~0); knn_mean = mean sqrt(vA[1..5])
    const float mean = (sqrtf(vA[1]) + sqrtf(vA[2]) + sqrtf(vA[3]) +
                        sqrtf(vA[4]) + sqrtf(vA[5])) * 0.2f;
    term = logf(mean + 1e-8f);
  }
#pragma unroll
  for (int off = 32; off > 0; off >>= 1) term += __shfl_down(term, off, 64);
  __shared__ float red[4];
  if ((t & 63) == 0) red[t >> 6] = term;
  __syncthreads();
  if (t == 0) {
    atomicAdd(acc, red[0] + red[1] + red[2] + red[3]);
    __threadfence();
    const unsigned int tk = atomicAdd(tkt, 1u);
    if (tk == (B_DIM / 32) - 1) {
      const float total = atomicAdd(acc, 0.0f);  // coherent read of final sum
      out[0] = -total * (1.0f / 8192.0f);
    }
  }
}

extern "C" void kernel_launch(void* const* d_in, const int* in_sizes, int n_in,
                              void* d_out, int out_size, void* d_ws, size_t ws_size,
                              hipStream_t stream) {
  const float* x = (const float*)d_in[0];
  float* out = (float*)d_out;
  char* ws = (char*)d_ws;
  unsigned char* xb = (unsigned char*)(ws + WS_XB);
  float* sq = (float*)(ws + WS_SQ);
  float* cand = (float*)(ws + WS_CAND);
  float* acc = (float*)(ws + WS_ACC);
  unsigned int* tkt = (unsigned int*)(ws + WS_TKT);

  cast_sq_kernel<<<B_DIM / 4, 256, 0, stream>>>(x, xb, sq, acc, tkt);
  knn_gemm_kernel<<<NTILES, 256, 0, stream>>>(xb, sq, cand);
  knn_merge_kernel<<<B_DIM / 32, 256, 0, stream>>>(cand, acc, tkt, out);
}

// Round 16
// 130.065 us; speedup vs baseline: 1.5898x; 1.5898x over previous
//
#include <hip/hip_runtime.h>
#include <hip/hip_bf16.h>
#include <hip/hip_fp8.h>

#define D_DIM 768
#define B_DIM 8192
#define NT 64           // tile grid dim (8192/128)
#define NTILES 2080     // NT*(NT+1)/2 upper-triangle tiles
#define BM 128

typedef __attribute__((ext_vector_type(4))) float f32x4;
typedef __attribute__((ext_vector_type(2))) float f32x2;
typedef __attribute__((ext_vector_type(4))) int i32x4;
typedef __attribute__((ext_vector_type(8))) int i32x8;

// ws layout (bytes)
#define WS_XB   0                               // fp8[8192*768]    = 6,291,456
#define WS_SQ   6291456                         // float[8192]      = 32,768
#define WS_CAND 6324224                         // float[8192*64*6] = 12,582,912
#define WS_ACC  18907136                        // float[1]
#define WS_TKT  18907140                        // uint[1]

__device__ __forceinline__ void gl_lds16(const void* g, void* lds) {
  __builtin_amdgcn_global_load_lds(
      (const __attribute__((address_space(1))) unsigned int*)g,
      (__attribute__((address_space(3))) unsigned int*)lds, 16, 0, 0);
}

// sort 4 values ascending (5-comparator network, 10 VALU)
__device__ __forceinline__ void sort4(float& a0, float& a1, float& a2,
                                      float& a3) {
  const float s1 = fminf(a0, a1), t1 = fmaxf(a0, a1);
  const float s2 = fminf(a2, a3), t2 = fmaxf(a2, a3);
  const float lo = fminf(s1, s2), m1 = fmaxf(s1, s2);
  const float hi = fmaxf(t1, t2), m2 = fminf(t1, t2);
  a0 = lo;
  a1 = fminf(m1, m2);
  a2 = fmaxf(m1, m2);
  a3 = hi;
}

// merge sorted a[0..3] into sorted v[0..5], keep 6 smallest (closed-form
// k-th-of-union; nested fminf chains fuse to v_min3_f32)
__device__ __forceinline__ void mrg46(float a0, float a1, float a2, float a3,
                                      float* v) {
  const float x00 = fmaxf(v[0], a0);
  const float x01 = fmaxf(v[0], a1), x10 = fmaxf(v[1], a0);
  const float x02 = fmaxf(v[0], a2), x11 = fmaxf(v[1], a1),
              x20 = fmaxf(v[2], a0);
  const float x03 = fmaxf(v[0], a3), x12 = fmaxf(v[1], a2),
              x21 = fmaxf(v[2], a1), x30 = fmaxf(v[3], a0);
  const float x13 = fmaxf(v[1], a3), x22 = fmaxf(v[2], a2),
              x31 = fmaxf(v[3], a1), x40 = fmaxf(v[4], a0);
  const float m0 = fminf(v[0], a0);
  const float m1 = fminf(fminf(v[1], a1), x00);
  const float m2 = fminf(fminf(fminf(v[2], a2), x01), x10);
  const float m3 = fminf(fminf(fminf(v[3], a3), x02), fminf(x11, x20));
  const float m4 = fminf(fminf(fminf(v[4], x03), x12), fminf(x21, x30));
  const float m5 = fminf(fminf(fminf(v[5], x13), x22), fminf(x31, x40));
  v[0] = m0; v[1] = m1; v[2] = m2; v[3] = m3; v[4] = m4; v[5] = m5;
}

// merge sorted b[0..5] into sorted v[0..5], keep 6 smallest
__device__ __forceinline__ void mrg66(const float* b, float* v) {
  const float x00 = fmaxf(v[0], b[0]);
  const float x01 = fmaxf(v[0], b[1]), x10 = fmaxf(v[1], b[0]);
  const float x02 = fmaxf(v[0], b[2]), x11 = fmaxf(v[1], b[1]),
              x20 = fmaxf(v[2], b[0]);
  const float x03 = fmaxf(v[0], b[3]), x12 = fmaxf(v[1], b[2]),
              x21 = fmaxf(v[2], b[1]), x30 = fmaxf(v[3], b[0]);
  const float x04 = fmaxf(v[0], b[4]), x13 = fmaxf(v[1], b[3]),
              x22 = fmaxf(v[2], b[2]), x31 = fmaxf(v[3], b[1]),
              x40 = fmaxf(v[4], b[0]);
  const float m0 = fminf(v[0], b[0]);
  const float m1 = fminf(fminf(v[1], b[1]), x00);
  const float m2 = fminf(fminf(fminf(v[2], b[2]), x01), x10);
  const float m3 = fminf(fminf(fminf(v[3], b[3]), x02), fminf(x11, x20));
  const float m4 =
      fminf(fminf(fminf(v[4], b[4]), x03), fminf(fminf(x12, x21), x30));
  const float m5 = fminf(fminf(fminf(v[5], b[5]), x04),
                         fminf(fminf(x13, x22), fminf(x31, x40)));
  v[0] = m0; v[1] = m1; v[2] = m2; v[3] = m3; v[4] = m4; v[5] = m5;
}

// band-blocked triangle order (16x16-tile blocks, rt-major inside). g in [0,2080).
__device__ __forceinline__ void tile_decode(int g, int& rt, int& ct) {
  int base = 0;
  for (int s = 0; s < 4; ++s) {
    for (int cb = s; cb < 4; ++cb) {
      const int sz = (cb == s) ? 136 : 256;
      if (g < base + sz) {
        int loc = g - base;
        if (cb == s) {
          int r = 0;
          while (loc >= 16 - r) {
            loc -= 16 - r;
            ++r;
          }
          rt = s * 16 + r;
          ct = cb * 16 + r + loc;
        } else {
          rt = s * 16 + (loc >> 4);
          ct = cb * 16 + (loc & 15);
        }
        return;
      }
      base += sz;
    }
  }
  rt = 0;
  ct = 0;
}

// kernel 1: cast fp32 -> fp8 e4m3 (OCP), row sum-of-squares of the DECODED fp8
// values (so self-distance rsq+rsq-2*G(i,i) stays ~0). Verified round 9/10.
__global__ __launch_bounds__(256) void cast_sq_kernel(
    const float* __restrict__ x, unsigned char* __restrict__ xb,
    float* __restrict__ sq, float* __restrict__ acc,
    unsigned int* __restrict__ tkt) {
  const int t = threadIdx.x;
  const int w = t >> 6, lane = t & 63;
  const int row = blockIdx.x * 4 + w;
  if (blockIdx.x == 0) {
    if (t == 0) acc[0] = 0.0f;
    if (t == 1) tkt[0] = 0u;
  }
  const f32x4* xr = (const f32x4*)(x + (size_t)row * D_DIM);
  unsigned int* xbr = (unsigned int*)(xb + (size_t)row * D_DIM);
  float s = 0.0f;
#pragma unroll
  for (int c = 0; c < 3; ++c) {
    const int idx = c * 64 + lane;
    f32x4 v = xr[idx];
    unsigned int p = 0;
#pragma unroll
    for (int e = 0; e < 4; ++e) {
      __hip_fp8_e4m3 h(v[e]);
      const float d = (float)h;
      s += d * d;
      p |= ((unsigned int)h.__x) << (8 * e);
    }
    xbr[idx] = p;
  }
#pragma unroll
  for (int off = 32; off > 0; off >>= 1) s += __shfl_down(s, off, 64);
  if (lane == 0) sq[row] = s;
}

// ------- kernel 2: MX-fp8 K=128, single-buffer staging, 4 blocks/CU -------
// Round-15 schedule (functionally verified, absmax 0) with the register
// budget FIXED: __launch_bounds__(256,2) keeps the allocator at ~88 VGPR
// (r14-proven, no spills); actual occupancy is then resource-determined:
// 88 VGPR -> 128-step -> 4 waves/SIMD, LDS 33 KB x 4 = 132 KB -> 4 blocks/CU.
// (r15's (256,4) forced a 64-VGPR budget -> acv spilled to scratch ->
// 515 MB of HBM scratch traffic. That was the whole regression.)
#define VMW(N) asm volatile("s_waitcnt vmcnt(" #N ")" ::: "memory")
#define BAR()                         \
  {                                   \
    asm volatile("" ::: "memory");    \
    __builtin_amdgcn_s_barrier();     \
    asm volatile("" ::: "memory");    \
  }

__global__ __launch_bounds__(256, 2) void knn_gemm_kernel(
    const unsigned char* __restrict__ xb, const float* __restrict__ sq,
    float* __restrict__ cand) {
  __shared__ __align__(16) char smem[33792];
  const int t = threadIdx.x;
  const int lane = t & 63, w = t >> 6;
  const int wm = w >> 1, wn = w & 1;  // 2x2 wave grid; wave tile 64x64
  const int quad = lane >> 4, m16 = lane & 15;

  // XCD chunking (2080 = 8*260, bijective) + band-blocked decode
  const int g = (blockIdx.x & 7) * (NTILES / 8) + (blockIdx.x >> 3);
  int rt, ct;
  tile_decode(g, rt, ct);
  const bool offdiag = (ct > rt);
  const int rowBase = rt * BM, colBase = ct * BM;

  // staging: thread t covers rows (t>>3)+32q, slot t&7; inverse slot swizzle on
  // the global source. (row&3) and ((row>>2)&1) are invariant under row+=32.
  const int sR = t >> 3, sS = t & 7;
  const int q_src = ((sS >> 1) - sR) & 3;
  const int h_src = ((sS & 1) - (sR >> 2)) & 1;
  const int srcOff = q_src * 32 + h_src * 16;
  const unsigned char* pA = xb + (size_t)(rowBase + sR) * D_DIM + srcOff;
  const unsigned char* pB = xb + (size_t)(colBase + sR) * D_DIM + srcOff;

  // fragment read offsets (within a row's 128 B)
  const int pairOff = ((quad + m16) & 3) * 32;
  const int bitOff = ((m16 >> 2) & 1) * 16;
  const int laneLo = m16 * 128 + pairOff + bitOff;
  const int laneHi = m16 * 128 + pairOff + (bitOff ^ 16);
  const int aRow = wm * 8192;
  const int bRow = wn * 8192;

  float rsq[16];
#pragma unroll
  for (int i = 0; i < 4; ++i)
#pragma unroll
    for (int r = 0; r < 4; ++r)
      rsq[i * 4 + r] = sq[rowBase + wm * 64 + i * 16 + quad * 4 + r];
  float csq[4];
#pragma unroll
  for (int j = 0; j < 4; ++j) csq[j] = sq[colBase + wn * 64 + j * 16 + m16];

  f32x4 acv[4][4];
  const f32x4 zero = {0.0f, 0.0f, 0.0f, 0.0f};
#pragma unroll
  for (int i = 0; i < 4; ++i)
#pragma unroll
    for (int j = 0; j < 4; ++j) acv[i][j] = zero;

#define STAGE(P, KOFF, REGION)                                          \
  {                                                                     \
    _Pragma("unroll") for (int q = 0; q < 4; ++q)                       \
        gl_lds16((P) + (KOFF) + q * 32 * D_DIM,                         \
                 smem + (REGION) + q * 4096 + t * 16);                  \
  }

  i32x8 aF[4], bF[4];
#define LDA(BASE)                                                            \
  {                                                                          \
    _Pragma("unroll") for (int ii = 0; ii < 4; ++ii) {                       \
      i32x4 lo = *(const i32x4*)(smem + (BASE) + aRow + ii * 2048 + laneLo); \
      i32x4 hi = *(const i32x4*)(smem + (BASE) + aRow + ii * 2048 + laneHi); \
      __builtin_memcpy(&aF[ii], &lo, 16);                                    \
      __builtin_memcpy(((char*)&aF[ii]) + 16, &hi, 16);                      \
    }                                                                        \
  }
#define LDB(BASE)                                                            \
  {                                                                          \
    _Pragma("unroll") for (int j = 0; j < 4; ++j) {                          \
      i32x4 lo = *(const i32x4*)(smem + (BASE) + bRow + j * 2048 + laneLo);  \
      i32x4 hi = *(const i32x4*)(smem + (BASE) + bRow + j * 2048 + laneHi);  \
      __builtin_memcpy(&bF[j], &lo, 16);                                     \
      __builtin_memcpy(((char*)&bF[j]) + 16, &hi, 16);                       \
    }                                                                        \
  }
#define MFMAS16                                                              \
  {                                                                          \
    __builtin_amdgcn_s_setprio(1);                                           \
    _Pragma("unroll") for (int ii = 0; ii < 4; ++ii)                         \
        _Pragma("unroll") for (int j = 0; j < 4; ++j)                        \
            acv[ii][j] = __builtin_amdgcn_mfma_scale_f32_16x16x128_f8f6f4(   \
                aF[ii], bF[j], acv[ii][j], 0, 0, 0, 0x7F7F7F7F, 0,           \
                0x7F7F7F7F);                                                 \
    __builtin_amdgcn_s_setprio(0);                                           \
  }

  // prologue: stage section 0 into the single buffer (A at 0, B at 16384)
  STAGE(pA, 0, 0);
  STAGE(pB, 0, 16384);

#pragma unroll
  for (int s = 0; s < 6; ++s) {
    VMW(0);   // own staging loads arrived (each wave drains pre-barrier)
    BAR();    // -> all waves' staging visible
    LDA(0);
    LDB(16384);
    BAR();    // lgkm drained per-wave pre-barrier -> buffer free to overwrite
    if (s < 5) {
      STAGE(pA, (s + 1) * 128, 0);       // flies during the MFMA phase
      STAGE(pB, (s + 1) * 128, 16384);
    }
    MFMAS16;
  }

  // ---------------- epilogue: 2 groups of 64 rows, split row/col duty ----------------
  float* distS = (float*)smem;             // [64][132] f32 = 33792 B (full d^2)
  float colA[6], colB[6];
#pragma unroll
  for (int q = 0; q < 6; ++q) colA[q] = colB[q] = 1e30f;

#pragma unroll
  for (int gg = 0; gg < 2; ++gg) {
    BAR();  // all ds_reads of the K-loop buffer retired before overwrite
    if (wm == gg) {
      // full d^2 = (csq[col] + rsq[row]) - 2G
#pragma unroll
      for (int ii = 0; ii < 4; ++ii)
#pragma unroll
        for (int j = 0; j < 4; ++j)
#pragma unroll
          for (int r = 0; r < 4; ++r)
            distS[(ii * 16 + quad * 4 + r) * 132 + wn * 64 + j * 16 + m16] =
                (csq[j] + rsq[ii * 4 + r]) - 2.0f * acv[ii][j][r];
    }
    BAR();
    if (t < 128) {
      // row-side: 2 thr/row x 64 cols; dual independent chains (even/odd batch)
      const int row_l = t >> 1, half = t & 1;
      const float* drow = distS + row_l * 132 + half * 64;
      float vA[6], vB[6];
      {
        f32x4 dv = *(const f32x4*)(drow);
        float w0 = dv[0], w1 = dv[1], w2 = dv[2], w3 = dv[3];
        sort4(w0, w1, w2, w3);
        vA[0] = w0; vA[1] = w1; vA[2] = w2; vA[3] = w3;
        vA[4] = 1e30f; vA[5] = 1e30f;
      }
      {
        f32x4 dv = *(const f32x4*)(drow + 4);
        float w0 = dv[0], w1 = dv[1], w2 = dv[2], w3 = dv[3];
        sort4(w0, w1, w2, w3);
        vB[0] = w0; vB[1] = w1; vB[2] = w2; vB[3] = w3;
        vB[4] = 1e30f; vB[5] = 1e30f;
      }
#pragma unroll
      for (int k = 2; k < 16; k += 2) {
        {
          f32x4 dv = *(const f32x4*)(drow + k * 4);
          float w0 = dv[0], w1 = dv[1], w2 = dv[2], w3 = dv[3];
          sort4(w0, w1, w2, w3);
          mrg46(w0, w1, w2, w3, vA);
        }
        {
          f32x4 dv = *(const f32x4*)(drow + k * 4 + 4);
          float w0 = dv[0], w1 = dv[1], w2 = dv[2], w3 = dv[3];
          sort4(w0, w1, w2, w3);
          mrg46(w0, w1, w2, w3, vB);
        }
      }
      mrg66(vB, vA);
      float b[6];
#pragma unroll
      for (int q = 0; q < 6; ++q) b[q] = __shfl_xor(vA[q], 1, 64);
      mrg66(b, vA);
      if (half == 0) {
        const int grow = rowBase + gg * 64 + row_l;
        float* o6 = cand + (size_t)(grow * NT + ct) * 6;
        f32x2 w0 = {fmaxf(vA[0], 0.0f), fmaxf(vA[1], 0.0f)};
        f32x2 w1 = {fmaxf(vA[2], 0.0f), fmaxf(vA[3], 0.0f)};
        f32x2 w2 = {fmaxf(vA[4], 0.0f), fmaxf(vA[5], 0.0f)};
        *(f32x2*)o6 = w0;
        *(f32x2*)(o6 + 2) = w1;
        *(f32x2*)(o6 + 4) = w2;
      }
    } else if (offdiag) {
      // col-side: 1 thr/col; distS already holds full d^2; dual chains
      const int col = t - 128;
#pragma unroll
      for (int r4 = 0; r4 < 16; r4 += 2) {
        {
          const int rr = r4 * 4;
          float w0 = distS[(rr + 0) * 132 + col];
          float w1 = distS[(rr + 1) * 132 + col];
          float w2 = distS[(rr + 2) * 132 + col];
          float w3 = distS[(rr + 3) * 132 + col];
          sort4(w0, w1, w2, w3);
          mrg46(w0, w1, w2, w3, colA);
        }
        {
          const int rr = (r4 + 1) * 4;
          float w0 = distS[(rr + 0) * 132 + col];
          float w1 = distS[(rr + 1) * 132 + col];
          float w2 = distS[(rr + 2) * 132 + col];
          float w3 = distS[(rr + 3) * 132 + col];
          sort4(w0, w1, w2, w3);
          mrg46(w0, w1, w2, w3, colB);
        }
      }
    }
  }
  if (offdiag && t >= 128) {
    mrg66(colB, colA);
    const int colg = colBase + (t - 128);
    float* o6 = cand + (size_t)(colg * NT + rt) * 6;
    f32x2 w0 = {fmaxf(colA[0], 0.0f), fmaxf(colA[1], 0.0f)};
    f32x2 w1 = {fmaxf(colA[2], 0.0f), fmaxf(colA[3], 0.0f)};
    f32x2 w2 = {fmaxf(colA[4], 0.0f), fmaxf(colA[5], 0.0f)};
    *(f32x2*)o6 = w0;
    *(f32x2*)(o6 + 2) = w1;
    *(f32x2*)(o6 + 4) = w2;
  }
}

// kernel 3: per-row merge of 64 chunk-candidates (each already sorted-6)
// via two independent mrg66 chains -> sqrt -> log -> global sum, fused
// finalize via ticket (last block writes the output).
__global__ __launch_bounds__(256) void knn_merge_kernel(
    const float* __restrict__ cand, float* __restrict__ acc,
    unsigned int* __restrict__ tkt, float* __restrict__ out) {
  const int t = threadIdx.x;
  const int r = blockIdx.x * 32 + (t >> 3);
  const float* cr = cand + (size_t)r * (NT * 6) + (size_t)(t & 7) * 48;
  float vA[6], vB[6];
  {
    f32x4 d0 = *(const f32x4*)(cr);
    f32x4 d1 = *(const f32x4*)(cr + 4);
    f32x4 d2 = *(const f32x4*)(cr + 8);
    vA[0] = d0[0]; vA[1] = d0[1]; vA[2] = d0[2]; vA[3] = d0[3];
    vA[4] = d1[0]; vA[5] = d1[1];
    vB[0] = d1[2]; vB[1] = d1[3]; vB[2] = d2[0]; vB[3] = d2[1];
    vB[4] = d2[2]; vB[5] = d2[3];
  }
#pragma unroll
  for (int c = 1; c < 4; ++c) {
    f32x4 d0 = *(const f32x4*)(cr + c * 12);
    f32x4 d1 = *(const f32x4*)(cr + c * 12 + 4);
    f32x4 d2 = *(const f32x4*)(cr + c * 12 + 8);
    float b0[6] = {d0[0], d0[1], d0[2], d0[3], d1[0], d1[1]};
    mrg66(b0, vA);
    float b1[6] = {d1[2], d1[3], d2[0], d2[1], d2[2], d2[3]};
    mrg66(b1, vB);
  }
  mrg66(vB, vA);
#pragma unroll
  for (int st = 1; st <= 4; st <<= 1) {
    float b[6];
#pragma unroll
    for (int q = 0; q < 6; ++q) b[q] = __shfl_xor(vA[q], st, 64);
    mrg66(b, vA);
  }
  float term = 0.0f;
  if ((t & 7) == 0) {
    // vA sorted ascending on d^2: vA[0]=self (~0); knn_mean = mean sqrt(vA[1..5])
    const float mean = (sqrtf(vA[1]) + sqrtf(vA[2]) + sqrtf(vA[3]) +
                        sqrtf(vA[4]) + sqrtf(vA[5])) * 0.2f;
    term = logf(mean + 1e-8f);
  }
#pragma unroll
  for (int off = 32; off > 0; off >>= 1) term += __shfl_down(term, off, 64);
  __shared__ float red[4];
  if ((t & 63) == 0) red[t >> 6] = term;
  __syncthreads();
  if (t == 0) {
    atomicAdd(acc, red[0] + red[1] + red[2] + red[3]);
    __threadfence();
    const unsigned int tk = atomicAdd(tkt, 1u);
    if (tk == (B_DIM / 32) - 1) {
      const float total = atomicAdd(acc, 0.0f);  // coherent read of final sum
      out[0] = -total * (1.0f / 8192.0f);
    }
  }
}

extern "C" void kernel_launch(void* const* d_in, const int* in_sizes, int n_in,
                              void* d_out, int out_size, void* d_ws, size_t ws_size,
                              hipStream_t stream) {
  const float* x = (const float*)d_in[0];
  float* out = (float*)d_out;
  char* ws = (char*)d_ws;
  unsigned char* xb = (unsigned char*)(ws + WS_XB);
  float* sq = (float*)(ws + WS_SQ);
  float* cand = (float*)(ws + WS_CAND);
  float* acc = (float*)(ws + WS_ACC);
  unsigned int* tkt = (unsigned int*)(ws + WS_TKT);

  cast_sq_kernel<<<B_DIM / 4, 256, 0, stream>>>(x, xb, sq, acc, tkt);
  knn_gemm_kernel<<<NTILES, 256, 0, stream>>>(xb, sq, cand);
  knn_merge_kernel<<<B_DIM / 32, 256, 0, stream>>>(cand, acc, tkt, out);
}

// Round 17
// 129.129 us; speedup vs baseline: 1.6013x; 1.0073x over previous
//
#include <hip/hip_runtime.h>
#include <hip/hip_bf16.h>
#include <hip/hip_fp8.h>

#define D_DIM 768
#define B_DIM 8192
#define NT 64           // tile grid dim (8192/128)
#define NTILES 2080     // NT*(NT+1)/2 upper-triangle tiles
#define BM 128

typedef __attribute__((ext_vector_type(4))) float f32x4;
typedef __attribute__((ext_vector_type(2))) float f32x2;
typedef __attribute__((ext_vector_type(4))) int i32x4;
typedef __attribute__((ext_vector_type(8))) int i32x8;

// ws layout (bytes)
#define WS_XB   0                               // fp8[8192*768]    = 6,291,456
#define WS_SQ   6291456                         // float[8192]      = 32,768
#define WS_CAND 6324224                         // float[8192*64*6] = 12,582,912
#define WS_ACC  18907136                        // float[1]
#define WS_TKT  18907140                        // uint[1]

__device__ __forceinline__ void gl_lds16(const void* g, void* lds) {
  __builtin_amdgcn_global_load_lds(
      (const __attribute__((address_space(1))) unsigned int*)g,
      (__attribute__((address_space(3))) unsigned int*)lds, 16, 0, 0);
}

// sort 4 values ascending (5-comparator network, 10 VALU)
__device__ __forceinline__ void sort4(float& a0, float& a1, float& a2,
                                      float& a3) {
  const float s1 = fminf(a0, a1), t1 = fmaxf(a0, a1);
  const float s2 = fminf(a2, a3), t2 = fmaxf(a2, a3);
  const float lo = fminf(s1, s2), m1 = fmaxf(s1, s2);
  const float hi = fmaxf(t1, t2), m2 = fminf(t1, t2);
  a0 = lo;
  a1 = fminf(m1, m2);
  a2 = fmaxf(m1, m2);
  a3 = hi;
}

// merge sorted pair (a0 <= a1) into sorted v[0..5], keep 6 smallest.
// m_k = min(v_k, max(v_{k-1},a0), max(v_{k-2},a1)) - 15 VALU (mins fuse to
// v_min3). 17 ops per 2 values incl. the pair sort vs 42/4 for sort4+mrg46.
__device__ __forceinline__ void mrg26(float a0, float a1, float* v) {
  const float x0 = fmaxf(v[0], a0);
  const float x1 = fmaxf(v[1], a0), y1 = fmaxf(v[0], a1);
  const float x2 = fmaxf(v[2], a0), y2 = fmaxf(v[1], a1);
  const float x3 = fmaxf(v[3], a0), y3 = fmaxf(v[2], a1);
  const float x4 = fmaxf(v[4], a0), y4 = fmaxf(v[3], a1);
  const float m0 = fminf(v[0], a0);
  const float m1 = fminf(fminf(v[1], x0), a1);
  const float m2 = fminf(fminf(v[2], x1), y1);
  const float m3 = fminf(fminf(v[3], x2), y2);
  const float m4 = fminf(fminf(v[4], x3), y3);
  const float m5 = fminf(fminf(v[5], x4), y4);
  v[0] = m0; v[1] = m1; v[2] = m2; v[3] = m3; v[4] = m4; v[5] = m5;
}

// process one f32x4 as two pair-merges (34 VALU vs 42)
__device__ __forceinline__ void batch4(f32x4 dv, float* v) {
  mrg26(fminf(dv[0], dv[1]), fmaxf(dv[0], dv[1]), v);
  mrg26(fminf(dv[2], dv[3]), fmaxf(dv[2], dv[3]), v);
}

// merge sorted b[0..5] into sorted v[0..5], keep 6 smallest
__device__ __forceinline__ void mrg66(const float* b, float* v) {
  const float x00 = fmaxf(v[0], b[0]);
  const float x01 = fmaxf(v[0], b[1]), x10 = fmaxf(v[1], b[0]);
  const float x02 = fmaxf(v[0], b[2]), x11 = fmaxf(v[1], b[1]),
              x20 = fmaxf(v[2], b[0]);
  const float x03 = fmaxf(v[0], b[3]), x12 = fmaxf(v[1], b[2]),
              x21 = fmaxf(v[2], b[1]), x30 = fmaxf(v[3], b[0]);
  const float x04 = fmaxf(v[0], b[4]), x13 = fmaxf(v[1], b[3]),
              x22 = fmaxf(v[2], b[2]), x31 = fmaxf(v[3], b[1]),
              x40 = fmaxf(v[4], b[0]);
  const float m0 = fminf(v[0], b[0]);
  const float m1 = fminf(fminf(v[1], b[1]), x00);
  const float m2 = fminf(fminf(fminf(v[2], b[2]), x01), x10);
  const float m3 = fminf(fminf(fminf(v[3], b[3]), x02), fminf(x11, x20));
  const float m4 =
      fminf(fminf(fminf(v[4], b[4]), x03), fminf(fminf(x12, x21), x30));
  const float m5 = fminf(fminf(fminf(v[5], b[5]), x04),
                         fminf(fminf(x13, x22), fminf(x31, x40)));
  v[0] = m0; v[1] = m1; v[2] = m2; v[3] = m3; v[4] = m4; v[5] = m5;
}

// band-blocked triangle order (16x16-tile blocks, rt-major inside). g in [0,2080).
__device__ __forceinline__ void tile_decode(int g, int& rt, int& ct) {
  int base = 0;
  for (int s = 0; s < 4; ++s) {
    for (int cb = s; cb < 4; ++cb) {
      const int sz = (cb == s) ? 136 : 256;
      if (g < base + sz) {
        int loc = g - base;
        if (cb == s) {
          int r = 0;
          while (loc >= 16 - r) {
            loc -= 16 - r;
            ++r;
          }
          rt = s * 16 + r;
          ct = cb * 16 + r + loc;
        } else {
          rt = s * 16 + (loc >> 4);
          ct = cb * 16 + (loc & 15);
        }
        return;
      }
      base += sz;
    }
  }
  rt = 0;
  ct = 0;
}

// kernel 1: cast fp32 -> fp8 e4m3 (OCP), row sum-of-squares of the DECODED fp8
// values (so self-distance rsq+rsq-2*G(i,i) stays ~0). Verified round 9/10.
__global__ __launch_bounds__(256) void cast_sq_kernel(
    const float* __restrict__ x, unsigned char* __restrict__ xb,
    float* __restrict__ sq, float* __restrict__ acc,
    unsigned int* __restrict__ tkt) {
  const int t = threadIdx.x;
  const int w = t >> 6, lane = t & 63;
  const int row = blockIdx.x * 4 + w;
  if (blockIdx.x == 0) {
    if (t == 0) acc[0] = 0.0f;
    if (t == 1) tkt[0] = 0u;
  }
  const f32x4* xr = (const f32x4*)(x + (size_t)row * D_DIM);
  unsigned int* xbr = (unsigned int*)(xb + (size_t)row * D_DIM);
  float s = 0.0f;
#pragma unroll
  for (int c = 0; c < 3; ++c) {
    const int idx = c * 64 + lane;
    f32x4 v = xr[idx];
    unsigned int p = 0;
#pragma unroll
    for (int e = 0; e < 4; ++e) {
      __hip_fp8_e4m3 h(v[e]);
      const float d = (float)h;
      s += d * d;
      p |= ((unsigned int)h.__x) << (8 * e);
    }
    xbr[idx] = p;
  }
#pragma unroll
  for (int off = 32; off > 0; off >>= 1) s += __shfl_down(s, off, 64);
  if (lane == 0) sq[row] = s;
}

// ------- kernel 2: MX-fp8 K=128, single-buffer staging (r16, best: 57.8 us) -------
// Selection now uses pair-merges (mrg26, 8.5 VALU/value vs 10.5) - VALUBusy 41%
// is the top pipe and selection dominates it.
#define VMW(N) asm volatile("s_waitcnt vmcnt(" #N ")" ::: "memory")
#define BAR()                         \
  {                                   \
    asm volatile("" ::: "memory");    \
    __builtin_amdgcn_s_barrier();     \
    asm volatile("" ::: "memory");    \
  }

__global__ __launch_bounds__(256, 2) void knn_gemm_kernel(
    const unsigned char* __restrict__ xb, const float* __restrict__ sq,
    float* __restrict__ cand) {
  __shared__ __align__(16) char smem[33792];
  const int t = threadIdx.x;
  const int lane = t & 63, w = t >> 6;
  const int wm = w >> 1, wn = w & 1;  // 2x2 wave grid; wave tile 64x64
  const int quad = lane >> 4, m16 = lane & 15;

  // XCD chunking (2080 = 8*260, bijective) + band-blocked decode
  const int g = (blockIdx.x & 7) * (NTILES / 8) + (blockIdx.x >> 3);
  int rt, ct;
  tile_decode(g, rt, ct);
  const bool offdiag = (ct > rt);
  const int rowBase = rt * BM, colBase = ct * BM;

  // staging: thread t covers rows (t>>3)+32q, slot t&7; inverse slot swizzle on
  // the global source. (row&3) and ((row>>2)&1) are invariant under row+=32.
  const int sR = t >> 3, sS = t & 7;
  const int q_src = ((sS >> 1) - sR) & 3;
  const int h_src = ((sS & 1) - (sR >> 2)) & 1;
  const int srcOff = q_src * 32 + h_src * 16;
  const unsigned char* pA = xb + (size_t)(rowBase + sR) * D_DIM + srcOff;
  const unsigned char* pB = xb + (size_t)(colBase + sR) * D_DIM + srcOff;

  // fragment read offsets (within a row's 128 B)
  const int pairOff = ((quad + m16) & 3) * 32;
  const int bitOff = ((m16 >> 2) & 1) * 16;
  const int laneLo = m16 * 128 + pairOff + bitOff;
  const int laneHi = m16 * 128 + pairOff + (bitOff ^ 16);
  const int aRow = wm * 8192;
  const int bRow = wn * 8192;

  float rsq[16];
#pragma unroll
  for (int i = 0; i < 4; ++i)
#pragma unroll
    for (int r = 0; r < 4; ++r)
      rsq[i * 4 + r] = sq[rowBase + wm * 64 + i * 16 + quad * 4 + r];
  float csq[4];
#pragma unroll
  for (int j = 0; j < 4; ++j) csq[j] = sq[colBase + wn * 64 + j * 16 + m16];

  f32x4 acv[4][4];
  const f32x4 zero = {0.0f, 0.0f, 0.0f, 0.0f};
#pragma unroll
  for (int i = 0; i < 4; ++i)
#pragma unroll
    for (int j = 0; j < 4; ++j) acv[i][j] = zero;

#define STAGE(P, KOFF, REGION)                                          \
  {                                                                     \
    _Pragma("unroll") for (int q = 0; q < 4; ++q)                       \
        gl_lds16((P) + (KOFF) + q * 32 * D_DIM,                         \
                 smem + (REGION) + q * 4096 + t * 16);                  \
  }

  i32x8 aF[4], bF[4];
#define LDA(BASE)                                                            \
  {                                                                          \
    _Pragma("unroll") for (int ii = 0; ii < 4; ++ii) {                       \
      i32x4 lo = *(const i32x4*)(smem + (BASE) + aRow + ii * 2048 + laneLo); \
      i32x4 hi = *(const i32x4*)(smem + (BASE) + aRow + ii * 2048 + laneHi); \
      __builtin_memcpy(&aF[ii], &lo, 16);                                    \
      __builtin_memcpy(((char*)&aF[ii]) + 16, &hi, 16);                      \
    }                                                                        \
  }
#define LDB(BASE)                                                            \
  {                                                                          \
    _Pragma("unroll") for (int j = 0; j < 4; ++j) {                          \
      i32x4 lo = *(const i32x4*)(smem + (BASE) + bRow + j * 2048 + laneLo);  \
      i32x4 hi = *(const i32x4*)(smem + (BASE) + bRow + j * 2048 + laneHi);  \
      __builtin_memcpy(&bF[j], &lo, 16);                                     \
      __builtin_memcpy(((char*)&bF[j]) + 16, &hi, 16);                       \
    }                                                                        \
  }
#define MFMAS16                                                              \
  {                                                                          \
    __builtin_amdgcn_s_setprio(1);                                           \
    _Pragma("unroll") for (int ii = 0; ii < 4; ++ii)                         \
        _Pragma("unroll") for (int j = 0; j < 4; ++j)                        \
            acv[ii][j] = __builtin_amdgcn_mfma_scale_f32_16x16x128_f8f6f4(   \
                aF[ii], bF[j], acv[ii][j], 0, 0, 0, 0x7F7F7F7F, 0,           \
                0x7F7F7F7F);                                                 \
    __builtin_amdgcn_s_setprio(0);                                           \
  }

  // prologue: stage section 0 into the single buffer (A at 0, B at 16384)
  STAGE(pA, 0, 0);
  STAGE(pB, 0, 16384);

#pragma unroll
  for (int s = 0; s < 6; ++s) {
    VMW(0);   // own staging loads arrived (each wave drains pre-barrier)
    BAR();    // -> all waves' staging visible
    LDA(0);
    LDB(16384);
    BAR();    // lgkm drained per-wave pre-barrier -> buffer free to overwrite
    if (s < 5) {
      STAGE(pA, (s + 1) * 128, 0);       // flies during the MFMA phase
      STAGE(pB, (s + 1) * 128, 16384);
    }
    MFMAS16;
  }

  // ---------------- epilogue: 2 groups of 64 rows, split row/col duty ----------------
  float* distS = (float*)smem;             // [64][132] f32 = 33792 B (full d^2)
  float colA[6], colB[6];
#pragma unroll
  for (int q = 0; q < 6; ++q) colA[q] = colB[q] = 1e30f;

#pragma unroll
  for (int gg = 0; gg < 2; ++gg) {
    BAR();  // all ds_reads of the K-loop buffer retired before overwrite
    if (wm == gg) {
      // full d^2 = (csq[col] + rsq[row]) - 2G
#pragma unroll
      for (int ii = 0; ii < 4; ++ii)
#pragma unroll
        for (int j = 0; j < 4; ++j)
#pragma unroll
          for (int r = 0; r < 4; ++r)
            distS[(ii * 16 + quad * 4 + r) * 132 + wn * 64 + j * 16 + m16] =
                (csq[j] + rsq[ii * 4 + r]) - 2.0f * acv[ii][j][r];
    }
    BAR();
    if (t < 128) {
      // row-side: 2 thr/row x 64 cols; dual independent chains (even/odd batch)
      const int row_l = t >> 1, half = t & 1;
      const float* drow = distS + row_l * 132 + half * 64;
      float vA[6], vB[6];
      {
        f32x4 dv = *(const f32x4*)(drow);
        float w0 = dv[0], w1 = dv[1], w2 = dv[2], w3 = dv[3];
        sort4(w0, w1, w2, w3);
        vA[0] = w0; vA[1] = w1; vA[2] = w2; vA[3] = w3;
        vA[4] = 1e30f; vA[5] = 1e30f;
      }
      {
        f32x4 dv = *(const f32x4*)(drow + 4);
        float w0 = dv[0], w1 = dv[1], w2 = dv[2], w3 = dv[3];
        sort4(w0, w1, w2, w3);
        vB[0] = w0; vB[1] = w1; vB[2] = w2; vB[3] = w3;
        vB[4] = 1e30f; vB[5] = 1e30f;
      }
#pragma unroll
      for (int k = 2; k < 16; k += 2) {
        batch4(*(const f32x4*)(drow + k * 4), vA);
        batch4(*(const f32x4*)(drow + k * 4 + 4), vB);
      }
      mrg66(vB, vA);
      float b[6];
#pragma unroll
      for (int q = 0; q < 6; ++q) b[q] = __shfl_xor(vA[q], 1, 64);
      mrg66(b, vA);
      if (half == 0) {
        const int grow = rowBase + gg * 64 + row_l;
        float* o6 = cand + (size_t)(grow * NT + ct) * 6;
        f32x2 w0 = {fmaxf(vA[0], 0.0f), fmaxf(vA[1], 0.0f)};
        f32x2 w1 = {fmaxf(vA[2], 0.0f), fmaxf(vA[3], 0.0f)};
        f32x2 w2 = {fmaxf(vA[4], 0.0f), fmaxf(vA[5], 0.0f)};
        *(f32x2*)o6 = w0;
        *(f32x2*)(o6 + 2) = w1;
        *(f32x2*)(o6 + 4) = w2;
      }
    } else if (offdiag) {
      // col-side: 1 thr/col; distS already holds full d^2; dual chains
      const int col = t - 128;
#pragma unroll
      for (int r4 = 0; r4 < 16; r4 += 2) {
        {
          const int rr = r4 * 4;
          f32x4 dv = {distS[(rr + 0) * 132 + col], distS[(rr + 1) * 132 + col],
                      distS[(rr + 2) * 132 + col], distS[(rr + 3) * 132 + col]};
          batch4(dv, colA);
        }
        {
          const int rr = (r4 + 1) * 4;
          f32x4 dv = {distS[(rr + 0) * 132 + col], distS[(rr + 1) * 132 + col],
                      distS[(rr + 2) * 132 + col], distS[(rr + 3) * 132 + col]};
          batch4(dv, colB);
        }
      }
    }
  }
  if (offdiag && t >= 128) {
    mrg66(colB, colA);
    const int colg = colBase + (t - 128);
    float* o6 = cand + (size_t)(colg * NT + rt) * 6;
    f32x2 w0 = {fmaxf(colA[0], 0.0f), fmaxf(colA[1], 0.0f)};
    f32x2 w1 = {fmaxf(colA[2], 0.0f), fmaxf(colA[3], 0.0f)};
    f32x2 w2 = {fmaxf(colA[4], 0.0f), fmaxf(colA[5], 0.0f)};
    *(f32x2*)o6 = w0;
    *(f32x2*)(o6 + 2) = w1;
    *(f32x2*)(o6 + 4) = w2;
  }
}

// kernel 3: per-row merge of 64 chunk-candidates (each already sorted-6)
// via two independent mrg66 chains -> sqrt -> log -> global sum, fused
// finalize via ticket (last block writes the output).
__global__ __launch_bounds__(256) void knn_merge_kernel(
    const float* __restrict__ cand, float* __restrict__ acc,
    unsigned int* __restrict__ tkt, float* __restrict__ out) {
  const int t = threadIdx.x;
  const int r = blockIdx.x * 32 + (t >> 3);
  const float* cr = cand + (size_t)r * (NT * 6) + (size_t)(t & 7) * 48;
  float vA[6], vB[6];
  {
    f32x4 d0 = *(const f32x4*)(cr);
    f32x4 d1 = *(const f32x4*)(cr + 4);
    f32x4 d2 = *(const f32x4*)(cr + 8);
    vA[0] = d0[0]; vA[1] = d0[1]; vA[2] = d0[2]; vA[3] = d0[3];
    vA[4] = d1[0]; vA[5] = d1[1];
    vB[0] = d1[2]; vB[1] = d1[3]; vB[2] = d2[0]; vB[3] = d2[1];
    vB[4] = d2[2]; vB[5] = d2[3];
  }
#pragma unroll
  for (int c = 1; c < 4; ++c) {
    f32x4 d0 = *(const f32x4*)(cr + c * 12);
    f32x4 d1 = *(const f32x4*)(cr + c * 12 + 4);
    f32x4 d2 = *(const f32x4*)(cr + c * 12 + 8);
    float b0[6] = {d0[0], d0[1], d0[2], d0[3], d1[0], d1[1]};
    mrg66(b0, vA);
    float b1[6] = {d1[2], d1[3], d2[0], d2[1], d2[2], d2[3]};
    mrg66(b1, vB);
  }
  mrg66(vB, vA);
#pragma unroll
  for (int st = 1; st <= 4; st <<= 1) {
    float b[6];
#pragma unroll
    for (int q = 0; q < 6; ++q) b[q] = __shfl_xor(vA[q], st, 64);
    mrg66(b, vA);
  }
  float term = 0.0f;
  if ((t & 7) == 0) {
    // vA sorted ascending on d^2: vA[0]=self (~0); knn_mean = mean sqrt(vA[1..5])
    const float mean = (sqrtf(vA[1]) + sqrtf(vA[2]) + sqrtf(vA[3]) +
                        sqrtf(vA[4]) + sqrtf(vA[5])) * 0.2f;
    term = logf(mean + 1e-8f);
  }
#pragma unroll
  for (int off = 32; off > 0; off >>= 1) term += __shfl_down(term, off, 64);
  __shared__ float red[4];
  if ((t & 63) == 0) red[t >> 6] = term;
  __syncthreads();
  if (t == 0) {
    atomicAdd(acc, red[0] + red[1] + red[2] + red[3]);
    __threadfence();
    const unsigned int tk = atomicAdd(tkt, 1u);
    if (tk == (B_DIM / 32) - 1) {
      const float total = atomicAdd(acc, 0.0f);  // coherent read of final sum
      out[0] = -total * (1.0f / 8192.0f);
    }
  }
}

extern "C" void kernel_launch(void* const* d_in, const int* in_sizes, int n_in,
                              void* d_out, int out_size, void* d_ws, size_t ws_size,
                              hipStream_t stream) {
  const float* x = (const float*)d_in[0];
  float* out = (float*)d_out;
  char* ws = (char*)d_ws;
  unsigned char* xb = (unsigned char*)(ws + WS_XB);
  float* sq = (float*)(ws + WS_SQ);
  float* cand = (float*)(ws + WS_CAND);
  float* acc = (float*)(ws + WS_ACC);
  unsigned int* tkt = (unsigned int*)(ws + WS_TKT);

  cast_sq_kernel<<<B_DIM / 4, 256, 0, stream>>>(x, xb, sq, acc, tkt);
  knn_gemm_kernel<<<NTILES, 256, 0, stream>>>(xb, sq, cand);
  knn_merge_kernel<<<B_DIM / 32, 256, 0, stream>>>(cand, acc, tkt, out);
}